// Round 1
// baseline (806.238 us; speedup 1.0000x reference)
//
#include <hip/hip_runtime.h>

// article_concat: [256, 2048, 300] fp32  (d_in[0])
// options_concat: [256,   64, 300] fp32  (d_in[1])
// out:            [256, 600]       fp32
//
// Memory-bound mean-pool over the word axis. DIM=300 = 75 float4 columns.
// Block = 300 threads: t -> (rsub = t/75 in [0,4), j = t%75 in [0,75)).
// Each thread sums float4 column j over rows w ≡ rsub (mod 4) of its chunk,
// LDS-reduces across rsub, then accumulates to out.

#define B        256
#define DIM      300
#define J4       75          // DIM/4 float4 columns
#define W_ART    2048
#define W_OPT    64
#define ART_SPLIT 8          // blockIdx.y in [0,8) -> article chunks; y==8 -> options
#define ROWS_ART (W_ART / ART_SPLIT)   // 256 rows per article block

__global__ __launch_bounds__(DIM) void meanpool_concat_kernel(
    const float4* __restrict__ art,   // [B][2048][75]
    const float4* __restrict__ opt,   // [B][64][75]
    float* __restrict__ out)          // [B][600], article half pre-zeroed
{
    const int b    = blockIdx.x;
    const int y    = blockIdx.y;
    const int t    = threadIdx.x;
    const int rsub = t / J4;          // 0..3
    const int j    = t % J4;          // 0..74

    __shared__ float4 lds[DIM];

    float4 acc = make_float4(0.f, 0.f, 0.f, 0.f);

    if (y < ART_SPLIT) {
        // ---- article chunk: rows [y*256, y*256+256) ----
        const float4* slab = art + (size_t)b * (W_ART * J4);
        const int w0 = y * ROWS_ART;
        #pragma unroll 4
        for (int it = 0; it < ROWS_ART / 4; ++it) {
            const int w = w0 + it * 4 + rsub;
            const float4 v = slab[(size_t)w * J4 + j];
            acc.x += v.x; acc.y += v.y; acc.z += v.z; acc.w += v.w;
        }
        lds[t] = acc;
        __syncthreads();
        if (t < J4) {
            const float4 a = lds[t], bb = lds[t + J4],
                         c = lds[t + 2 * J4], d = lds[t + 3 * J4];
            const float s = 1.0f / (float)W_ART;
            float* o = out + (size_t)b * (2 * DIM) + 4 * t;
            atomicAdd(o + 0, (a.x + bb.x + c.x + d.x) * s);
            atomicAdd(o + 1, (a.y + bb.y + c.y + d.y) * s);
            atomicAdd(o + 2, (a.z + bb.z + c.z + d.z) * s);
            atomicAdd(o + 3, (a.w + bb.w + c.w + d.w) * s);
        }
    } else {
        // ---- options: all 64 rows in one block ----
        const float4* slab = opt + (size_t)b * (W_OPT * J4);
        #pragma unroll 4
        for (int it = 0; it < W_OPT / 4; ++it) {
            const int w = it * 4 + rsub;
            const float4 v = slab[(size_t)w * J4 + j];
            acc.x += v.x; acc.y += v.y; acc.z += v.z; acc.w += v.w;
        }
        lds[t] = acc;
        __syncthreads();
        if (t < J4) {
            const float4 a = lds[t], bb = lds[t + J4],
                         c = lds[t + 2 * J4], d = lds[t + 3 * J4];
            const float s = 1.0f / (float)W_OPT;
            float* o = out + (size_t)b * (2 * DIM) + DIM + 4 * t;
            o[0] = (a.x + bb.x + c.x + d.x) * s;
            o[1] = (a.y + bb.y + c.y + d.y) * s;
            o[2] = (a.z + bb.z + c.z + d.z) * s;
            o[3] = (a.w + bb.w + c.w + d.w) * s;
        }
    }
}

extern "C" void kernel_launch(void* const* d_in, const int* in_sizes, int n_in,
                              void* d_out, int out_size, void* d_ws, size_t ws_size,
                              hipStream_t stream) {
    const float4* art = (const float4*)d_in[0];
    const float4* opt = (const float4*)d_in[1];
    float* out = (float*)d_out;

    // Article half accumulates via atomicAdd -> zero the (poisoned) output first.
    hipMemsetAsync(d_out, 0, (size_t)out_size * sizeof(float), stream);

    dim3 grid(B, ART_SPLIT + 1);   // y<8: article chunks, y==8: options
    dim3 block(DIM);
    meanpool_concat_kernel<<<grid, block, 0, stream>>>(art, opt, out);
}

// Round 2
// 804.114 us; speedup vs baseline: 1.0026x; 1.0026x over previous
//
#include <hip/hip_runtime.h>

// article_concat: [256, 2048, 300] fp32  (d_in[0])
// options_concat: [256,   64, 300] fp32  (d_in[1])
// out:            [256, 600]       fp32
//
// Two-phase mean-pool (no atomics, no output memset):
//  Phase 1: grid (256 b, 8 y). Each block sums a contiguous 256-row chunk of
//    article[b]. 300 threads read the chunk as a flat float4 stream
//    (f = it*300 + t), so column j = t%75 is constant per thread -> register
//    accumulation, fully coalesced 4800 B per block-iteration. Two independent
//    accumulators + unroll 4 keep 8 loads in flight per thread. LDS-reduce the
//    4 row-phases, write float4 partial to d_ws.
//  Phase 2: grid (256 b), 300 threads. Thread c sums the 8 partials for
//    out[b][c] and the 64 option rows for out[b][300+c]. Every output element
//    written exactly once.

#define B        256
#define DIM      300
#define J4       75                       // DIM/4 float4 columns
#define W_ART    2048
#define W_OPT    64
#define SPLIT    8
#define ROWS_PB  (W_ART / SPLIT)          // 256 rows per phase-1 block
#define ITERS    (ROWS_PB * J4 / DIM)     // 64 float4 loads per thread

__global__ __launch_bounds__(DIM) void art_partial_kernel(
    const float4* __restrict__ art,       // [B][2048][75]
    float4* __restrict__ part)            // [SPLIT][B][75]
{
    const int b = blockIdx.x;
    const int y = blockIdx.y;
    const int t = threadIdx.x;
    const int j = t % J4;

    const float4* base = art + (size_t)b * (W_ART * J4) + (size_t)y * (ROWS_PB * J4);

    float4 a0 = make_float4(0.f, 0.f, 0.f, 0.f);
    float4 a1 = make_float4(0.f, 0.f, 0.f, 0.f);
    #pragma unroll 4
    for (int it = 0; it < ITERS; it += 2) {
        const float4 v0 = base[(size_t)(it + 0) * DIM + t];
        const float4 v1 = base[(size_t)(it + 1) * DIM + t];
        a0.x += v0.x; a0.y += v0.y; a0.z += v0.z; a0.w += v0.w;
        a1.x += v1.x; a1.y += v1.y; a1.z += v1.z; a1.w += v1.w;
    }
    a0.x += a1.x; a0.y += a1.y; a0.z += a1.z; a0.w += a1.w;

    __shared__ float4 lds[DIM];
    lds[t] = a0;
    __syncthreads();
    if (t < J4) {
        const float4 p0 = lds[t],          p1 = lds[t + J4],
                     p2 = lds[t + 2 * J4], p3 = lds[t + 3 * J4];
        float4 r;
        r.x = p0.x + p1.x + p2.x + p3.x;
        r.y = p0.y + p1.y + p2.y + p3.y;
        r.z = p0.z + p1.z + p2.z + p3.z;
        r.w = p0.w + p1.w + p2.w + p3.w;
        part[((size_t)y * B + b) * J4 + j] = r;
    }
}

__global__ __launch_bounds__(DIM) void finalize_kernel(
    const float* __restrict__ part,       // [SPLIT][B][300]
    const float* __restrict__ opt,        // [B][64][300]
    float* __restrict__ out)              // [B][600]
{
    const int b = blockIdx.x;
    const int c = threadIdx.x;            // 0..299

    float s = 0.f;
    #pragma unroll
    for (int y = 0; y < SPLIT; ++y)
        s += part[((size_t)y * B + b) * DIM + c];

    const float* ob = opt + (size_t)b * (W_OPT * DIM);
    float o0 = 0.f, o1 = 0.f;
    #pragma unroll 4
    for (int w = 0; w < W_OPT; w += 2) {
        o0 += ob[(size_t)(w + 0) * DIM + c];
        o1 += ob[(size_t)(w + 1) * DIM + c];
    }

    float* ou = out + (size_t)b * (2 * DIM);
    ou[c]       = s * (1.0f / (float)W_ART);
    ou[DIM + c] = (o0 + o1) * (1.0f / (float)W_OPT);
}

extern "C" void kernel_launch(void* const* d_in, const int* in_sizes, int n_in,
                              void* d_out, int out_size, void* d_ws, size_t ws_size,
                              hipStream_t stream) {
    const float4* art = (const float4*)d_in[0];
    const float*  opt = (const float*)d_in[1];
    float* out  = (float*)d_out;
    float4* part = (float4*)d_ws;         // needs SPLIT*B*300*4 = 2.4 MB of ws

    art_partial_kernel<<<dim3(B, SPLIT), dim3(DIM), 0, stream>>>(art, part);
    finalize_kernel<<<dim3(B), dim3(DIM), 0, stream>>>((const float*)part, opt, out);
}